// Round 2
// baseline (111.981 us; speedup 1.0000x reference)
//
#include <hip/hip_runtime.h>
#include <math.h>

#define B_   16
#define N_   32
#define I_   1152
#define DIN  16
#define D_   64
#define IB   72            // i-tiles of 16 in k_xhat
#define BND  (B_*N_*D_)    // 32768

#if __has_builtin(__builtin_amdgcn_exp2f)
#define EXP2(x) __builtin_amdgcn_exp2f(x)
#else
#define EXP2(x) exp2f(x)
#endif

#define LOG2E 1.4426950408889634f

__device__ __forceinline__ float squash1(float s) {
    float sq = s * s;
    return (sq / (1.0f + sq)) * s * rsqrtf(sq + 1e-9f);
}

// K1: x_hat[b][n][i][d] = dot16(W[n,i,d,:], inputs[b,i,:]); also per-block
// partial sums over the 16-i tile for s0 (deterministic, no atomics).
// Inputs are read via wave-uniform SCALAR loads (s_load) — no LDS staging.
// grid = N_*IB blocks, 256 threads. partials layout: part[ib][b][n][d].
__global__ __launch_bounds__(256) void k_xhat(const float* __restrict__ inp,
                                              const float* __restrict__ W,
                                              float* __restrict__ xh,
                                              float* __restrict__ part) {
    __shared__ float red[4096];            // [g][b][d] partial-reduce only (16 KB)
    const int bx = blockIdx.x;
    const int n  = bx / IB;
    const int ib = bx % IB;
    const int i0 = ib * 16;
    const int t  = threadIdx.x;
    const int d  = t & 63;
    const int g  = t >> 6;                 // wave id; each wave owns 4 i's

    float s0[B_];
    #pragma unroll
    for (int b = 0; b < B_; ++b) s0[b] = 0.0f;

    #pragma unroll
    for (int ii = 0; ii < 4; ++ii) {
        const int il = g * 4 + ii;
        const int i  = i0 + il;
        const float4* wp = (const float4*)(W + ((size_t)(n * I_ + i) * D_ + d) * DIN);
        float4 w0 = wp[0], w1 = wp[1], w2 = wp[2], w3 = wp[3];
        // wave-uniform input base -> provably uniform -> s_load path
        const int ibase = __builtin_amdgcn_readfirstlane(i) * DIN;
        #pragma unroll
        for (int b = 0; b < B_; ++b) {
            const float* __restrict__ q = inp + (size_t)b * (I_ * DIN) + ibase;
            float v = w0.x*q[0]  + w0.y*q[1]  + w0.z*q[2]  + w0.w*q[3]
                    + w1.x*q[4]  + w1.y*q[5]  + w1.z*q[6]  + w1.w*q[7]
                    + w2.x*q[8]  + w2.y*q[9]  + w2.z*q[10] + w2.w*q[11]
                    + w3.x*q[12] + w3.y*q[13] + w3.z*q[14] + w3.w*q[15];
            xh[((size_t)(b * N_ + n) * I_ + i) * D_ + d] = v;
            s0[b] += v;
        }
    }

    // reduce s0 over the 4 waves, one writer wave
    #pragma unroll
    for (int b = 0; b < B_; ++b) red[g * 1024 + b * 64 + d] = s0[b];
    __syncthreads();
    if (t < 64) {
        #pragma unroll
        for (int b = 0; b < B_; ++b) {
            float s = red[b * 64 + t] + red[1024 + b * 64 + t]
                    + red[2048 + b * 64 + t] + red[3072 + b * 64 + t];
            part[(size_t)ib * BND + (size_t)(b * N_ + n) * D_ + t] = s;
        }
    }
}

// K2: coef = squash(mean over i of x_hat) — iteration 0 (softmax of zeros is uniform)
__global__ __launch_bounds__(256) void k_out0(const float* __restrict__ part,
                                              float* __restrict__ coef) {
    const int t = blockIdx.x * 256 + threadIdx.x;   // 0..BND-1
    float s = 0.0f;
    for (int j = 0; j < IB; ++j) s += part[(size_t)j * BND + t];
    s *= (1.0f / (float)I_);
    coef[t] = squash1(s);
}

// K3/K4: one routing iteration. logits l_i = x_hat[b,n,i,d] * coef[b,n,d].
// Online softmax over i (exp2 domain, LOG2E folded into coef), s = sum c*x.
// final=0: coef += squash(s). final=1: out = squash(s).
// grid = B_*N_ blocks, 512 threads (8 i-stripes of 144, lane = d).
__global__ __launch_bounds__(512) void k_route(const float* __restrict__ xh,
                                               const float* __restrict__ coef_in,
                                               float* __restrict__ outp,
                                               int final_) {
    const int bx = blockIdx.x;             // b*N_ + n
    const int t  = threadIdx.x;
    const int d  = t & 63;
    const int g  = t >> 6;
    const float* base = xh + (size_t)bx * (I_ * D_);
    const float c  = coef_in[bx * D_ + d];
    const float c2 = c * LOG2E;

    float m = -INFINITY, Z = 0.0f, A = 0.0f;
    const int i0 = g * (I_ / 8);           // 144 per stripe
    #pragma unroll 4
    for (int j = 0; j < I_ / 8; ++j) {
        float x  = base[(size_t)(i0 + j) * D_ + d];
        float l  = x * c2;
        float nm = fmaxf(m, l);
        float e1 = EXP2(m - nm);
        float e2 = EXP2(l - nm);
        Z = Z * e1 + e2;
        A = A * e1 + e2 * x;
        m = nm;
    }

    __shared__ float ms[512], zs[512], as_[512];
    ms[t] = m; zs[t] = Z; as_[t] = A;
    __syncthreads();
    if (t < 64) {
        float M = -INFINITY;
        #pragma unroll
        for (int gg = 0; gg < 8; ++gg) M = fmaxf(M, ms[gg * 64 + t]);
        float Zt = 0.0f, At = 0.0f;
        #pragma unroll
        for (int gg = 0; gg < 8; ++gg) {
            float e = EXP2(ms[gg * 64 + t] - M);
            Zt += zs[gg * 64 + t] * e;
            At += as_[gg * 64 + t] * e;
        }
        float s = At / Zt;
        float o = squash1(s);
        if (final_) outp[bx * D_ + t] = o;
        else        outp[bx * D_ + t] = c + o;
    }
}

extern "C" void kernel_launch(void* const* d_in, const int* in_sizes, int n_in,
                              void* d_out, int out_size, void* d_ws, size_t ws_size,
                              hipStream_t stream) {
    const float* inp = (const float*)d_in[0];
    const float* W   = (const float*)d_in[1];
    float* out  = (float*)d_out;

    float* xh   = (float*)d_ws;                       // 37,748,736 floats (151 MB)
    float* part = xh + (size_t)B_ * N_ * I_ * D_;     // 72*32768 floats (9.4 MB)
    float* coef = part + (size_t)IB * BND;            // 32768 floats

    k_xhat <<<dim3(N_ * IB), dim3(256), 0, stream>>>(inp, W, xh, part);
    k_out0 <<<dim3(BND / 256), dim3(256), 0, stream>>>(part, coef);
    k_route<<<dim3(B_ * N_), dim3(512), 0, stream>>>(xh, coef, coef, 0);
    k_route<<<dim3(B_ * N_), dim3(512), 0, stream>>>(xh, coef, out, 1);
}

// Round 3
// 97.047 us; speedup vs baseline: 1.1539x; 1.1539x over previous
//
#include <hip/hip_runtime.h>
#include <hip/hip_bf16.h>
#include <math.h>

#define B_   16
#define N_   32
#define I_   1152
#define DIN  16
#define D_   64
#define IB   72            // i-tiles of 16 in k_xhat
#define BND  (B_*N_*D_)    // 32768

#if __has_builtin(__builtin_amdgcn_exp2f)
#define EXP2(x) __builtin_amdgcn_exp2f(x)
#else
#define EXP2(x) exp2f(x)
#endif

#define LOG2E 1.4426950408889634f

__device__ __forceinline__ float squash1(float s) {
    float sq = s * s;
    return (sq / (1.0f + sq)) * s * rsqrtf(sq + 1e-9f);
}

// K1: x_hat[b][n][i][d] = dot16(W[n,i,d,:], inputs[b,i,:]), stored as bf16.
// W loads are hand-pipelined 2-deep (prefetch issued BEFORE the store-heavy
// b-loop so counted vmcnt waits never drain the store queue). Inputs via
// wave-uniform scalar loads. Per-block partial sums for s0 (deterministic).
// grid = N_*IB blocks, 256 threads. partials layout: part[ib][b][n][d].
__global__ __launch_bounds__(256, 2) void k_xhat(const float* __restrict__ inp,
                                                 const float* __restrict__ W,
                                                 __hip_bfloat16* __restrict__ xh,
                                                 float* __restrict__ part) {
    __shared__ float red[4096];            // [g][b][d] partial-reduce (16 KB)
    const int bx = blockIdx.x;
    const int n  = bx / IB;
    const int ib = bx % IB;
    const int i0 = ib * 16;
    const int t  = threadIdx.x;
    const int d  = t & 63;
    const int g  = t >> 6;                 // wave id; each wave owns 4 i's

    float s0[B_];
    #pragma unroll
    for (int b = 0; b < B_; ++b) s0[b] = 0.0f;

#define LOADW(P0,P1,P2,P3,ii) {                                               \
        const float4* wp = (const float4*)(W +                                \
            ((size_t)(n * I_ + (i0 + g * 4 + (ii))) * D_ + d) * DIN);         \
        P0 = wp[0]; P1 = wp[1]; P2 = wp[2]; P3 = wp[3]; }

#define BODY(P0,P1,P2,P3,ii) {                                                \
        const int i = i0 + g * 4 + (ii);                                      \
        const int ibase = __builtin_amdgcn_readfirstlane(i) * DIN;            \
        _Pragma("unroll")                                                     \
        for (int b = 0; b < B_; ++b) {                                        \
            const float* __restrict__ q = inp + (size_t)b * (I_ * DIN) + ibase; \
            float v = P0.x*q[0]  + P0.y*q[1]  + P0.z*q[2]  + P0.w*q[3]        \
                    + P1.x*q[4]  + P1.y*q[5]  + P1.z*q[6]  + P1.w*q[7]        \
                    + P2.x*q[8]  + P2.y*q[9]  + P2.z*q[10] + P2.w*q[11]       \
                    + P3.x*q[12] + P3.y*q[13] + P3.z*q[14] + P3.w*q[15];      \
            xh[((size_t)(b * N_ + n) * I_ + i) * D_ + d] = __float2bfloat16(v); \
            s0[b] += v;                                                       \
        } }

    float4 A0, A1, A2, A3, Bb0, Bb1, Bb2, Bb3;
    LOADW(A0, A1, A2, A3, 0)
    LOADW(Bb0, Bb1, Bb2, Bb3, 1)
    BODY (A0, A1, A2, A3, 0)
    LOADW(A0, A1, A2, A3, 2)
    BODY (Bb0, Bb1, Bb2, Bb3, 1)
    LOADW(Bb0, Bb1, Bb2, Bb3, 3)
    BODY (A0, A1, A2, A3, 2)
    BODY (Bb0, Bb1, Bb2, Bb3, 3)
#undef LOADW
#undef BODY

    // reduce s0 over the 4 waves, one writer wave
    #pragma unroll
    for (int b = 0; b < B_; ++b) red[g * 1024 + b * 64 + d] = s0[b];
    __syncthreads();
    if (t < 64) {
        #pragma unroll
        for (int b = 0; b < B_; ++b) {
            float s = red[b * 64 + t] + red[1024 + b * 64 + t]
                    + red[2048 + b * 64 + t] + red[3072 + b * 64 + t];
            part[(size_t)ib * BND + (size_t)(b * N_ + n) * D_ + t] = s;
        }
    }
}

// K2: coef = squash(mean over i of x_hat) — iteration 0 (softmax of zeros is uniform)
__global__ __launch_bounds__(256) void k_out0(const float* __restrict__ part,
                                              float* __restrict__ coef) {
    const int t = blockIdx.x * 256 + threadIdx.x;   // 0..BND-1
    float s = 0.0f;
    for (int j = 0; j < IB; ++j) s += part[(size_t)j * BND + t];
    s *= (1.0f / (float)I_);
    coef[t] = squash1(s);
}

// K3/K4: one routing iteration over bf16 x_hat. logits l_i = x*coef.
// Online softmax over i (exp2 domain), s = sum c*x.
// final=0: coef += squash(s). final=1: out = squash(s).
// grid = B_*N_ blocks, 512 threads (8 i-stripes of 144, lane = d).
__global__ __launch_bounds__(512) void k_route(const __hip_bfloat16* __restrict__ xh,
                                               const float* __restrict__ coef_in,
                                               float* __restrict__ outp,
                                               int final_) {
    const int bx = blockIdx.x;             // b*N_ + n
    const int t  = threadIdx.x;
    const int d  = t & 63;
    const int g  = t >> 6;
    const __hip_bfloat16* base = xh + (size_t)bx * (I_ * D_);
    const float c  = coef_in[bx * D_ + d];
    const float c2 = c * LOG2E;

    float m = -INFINITY, Z = 0.0f, A = 0.0f;
    const int i0 = g * (I_ / 8);           // 144 per stripe
    #pragma unroll 4
    for (int j = 0; j < I_ / 8; ++j) {
        float x  = __bfloat162float(base[(size_t)(i0 + j) * D_ + d]);
        float l  = x * c2;
        float nm = fmaxf(m, l);
        float e1 = EXP2(m - nm);
        float e2 = EXP2(l - nm);
        Z = Z * e1 + e2;
        A = A * e1 + e2 * x;
        m = nm;
    }

    __shared__ float ms[512], zs[512], as_[512];
    ms[t] = m; zs[t] = Z; as_[t] = A;
    __syncthreads();
    if (t < 64) {
        float M = -INFINITY;
        #pragma unroll
        for (int gg = 0; gg < 8; ++gg) M = fmaxf(M, ms[gg * 64 + t]);
        float Zt = 0.0f, At = 0.0f;
        #pragma unroll
        for (int gg = 0; gg < 8; ++gg) {
            float e = EXP2(ms[gg * 64 + t] - M);
            Zt += zs[gg * 64 + t] * e;
            At += as_[gg * 64 + t] * e;
        }
        float s = At / Zt;
        float o = squash1(s);
        if (final_) outp[bx * D_ + t] = o;
        else        outp[bx * D_ + t] = c + o;
    }
}

extern "C" void kernel_launch(void* const* d_in, const int* in_sizes, int n_in,
                              void* d_out, int out_size, void* d_ws, size_t ws_size,
                              hipStream_t stream) {
    const float* inp = (const float*)d_in[0];
    const float* W   = (const float*)d_in[1];
    float* out  = (float*)d_out;

    __hip_bfloat16* xh = (__hip_bfloat16*)d_ws;               // 37,748,736 bf16 (75.5 MB)
    float* part = (float*)((char*)d_ws + (size_t)B_ * N_ * I_ * D_ * 2);  // 72*32768 floats
    float* coef = part + (size_t)IB * BND;                    // 32768 floats

    k_xhat <<<dim3(N_ * IB), dim3(256), 0, stream>>>(inp, W, xh, part);
    k_out0 <<<dim3(BND / 256), dim3(256), 0, stream>>>(part, coef);
    k_route<<<dim3(B_ * N_), dim3(512), 0, stream>>>(xh, coef, coef, 0);
    k_route<<<dim3(B_ * N_), dim3(512), 0, stream>>>(xh, coef, out, 1);
}

// Round 4
// 96.264 us; speedup vs baseline: 1.1633x; 1.0081x over previous
//
#include <hip/hip_runtime.h>
#include <hip/hip_bf16.h>
#include <math.h>

#define B_   16
#define N_   32
#define I_   1152
#define DIN  16
#define D_   64
#define IB   72            // i-tiles of 16 in k_xhat
#define BND  (B_*N_*D_)    // 32768

#if __has_builtin(__builtin_amdgcn_exp2f)
#define EXP2(x) __builtin_amdgcn_exp2f(x)
#else
#define EXP2(x) exp2f(x)
#endif

#define LOG2E 1.4426950408889634f

__device__ __forceinline__ float squash1(float s) {
    float sq = s * s;
    return (sq / (1.0f + sq)) * s * rsqrtf(sq + 1e-9f);
}

__device__ __forceinline__ unsigned short bf16bits(float v) {
    return __builtin_bit_cast(unsigned short, __float2bfloat16(v));
}

// K1: x_hat[b][n][i][d] = dot16(W[n,i,d,:], inputs[b,i,:]), stored as bf16.
// ALL outputs are accumulated in registers (packed 2 bf16 / u32); global
// stores are issued only at the very END (after the LDS reduce + barrier),
// so the W-load wait chain contains NO stores — counted vmcnt waits let the
// 2-deep W prefetch actually pipeline. Inputs via wave-uniform scalar loads.
// grid = N_*IB blocks, 256 threads. partials layout: part[ib][b][n][d].
__global__ __launch_bounds__(256, 4) void k_xhat(const float* __restrict__ inp,
                                                 const float* __restrict__ W,
                                                 __hip_bfloat16* __restrict__ xh,
                                                 float* __restrict__ part) {
    __shared__ float red[4096];            // [g][b][d] partial-reduce (16 KB)
    const int bx = blockIdx.x;
    const int n  = bx / IB;
    const int ib = bx % IB;
    const int i0 = ib * 16;
    const int t  = threadIdx.x;
    const int d  = t & 63;
    const int g  = t >> 6;                 // wave id; each wave owns 4 i's

    float s0[B_];
    #pragma unroll
    for (int b = 0; b < B_; ++b) s0[b] = 0.0f;

    unsigned int pk[4][8];                 // [ii][b/2]: (bf16(b+1)<<16)|bf16(b)

#define LOADW(P0,P1,P2,P3,ii) {                                               \
        const float4* wp = (const float4*)(W +                                \
            ((size_t)(n * I_ + (i0 + g * 4 + (ii))) * D_ + d) * DIN);         \
        P0 = wp[0]; P1 = wp[1]; P2 = wp[2]; P3 = wp[3]; }

#define BODY(P0,P1,P2,P3,ii) {                                                \
        const int i = i0 + g * 4 + (ii);                                      \
        const int ibase = __builtin_amdgcn_readfirstlane(i) * DIN;            \
        _Pragma("unroll")                                                     \
        for (int j = 0; j < 8; ++j) {                                         \
            const float* __restrict__ q0 = inp + (size_t)(2*j)   * (I_ * DIN) + ibase; \
            const float* __restrict__ q1 = inp + (size_t)(2*j+1) * (I_ * DIN) + ibase; \
            float v0 = P0.x*q0[0]  + P0.y*q0[1]  + P0.z*q0[2]  + P0.w*q0[3]   \
                     + P1.x*q0[4]  + P1.y*q0[5]  + P1.z*q0[6]  + P1.w*q0[7]   \
                     + P2.x*q0[8]  + P2.y*q0[9]  + P2.z*q0[10] + P2.w*q0[11]  \
                     + P3.x*q0[12] + P3.y*q0[13] + P3.z*q0[14] + P3.w*q0[15]; \
            float v1 = P0.x*q1[0]  + P0.y*q1[1]  + P0.z*q1[2]  + P0.w*q1[3]   \
                     + P1.x*q1[4]  + P1.y*q1[5]  + P1.z*q1[6]  + P1.w*q1[7]   \
                     + P2.x*q1[8]  + P2.y*q1[9]  + P2.z*q1[10] + P2.w*q1[11]  \
                     + P3.x*q1[12] + P3.y*q1[13] + P3.z*q1[14] + P3.w*q1[15]; \
            s0[2*j]   += v0;                                                  \
            s0[2*j+1] += v1;                                                  \
            pk[ii][j] = ((unsigned int)bf16bits(v1) << 16) | bf16bits(v0);    \
        } }

    float4 A0, A1, A2, A3, Bb0, Bb1, Bb2, Bb3;
    LOADW(A0, A1, A2, A3, 0)
    LOADW(Bb0, Bb1, Bb2, Bb3, 1)
    BODY (A0, A1, A2, A3, 0)
    LOADW(A0, A1, A2, A3, 2)
    BODY (Bb0, Bb1, Bb2, Bb3, 1)
    LOADW(Bb0, Bb1, Bb2, Bb3, 3)
    BODY (A0, A1, A2, A3, 2)
    BODY (Bb0, Bb1, Bb2, Bb3, 3)
#undef LOADW
#undef BODY

    // LDS reduce of s0 FIRST (register-only inputs), so the barrier does not
    // have to drain any global stores.
    #pragma unroll
    for (int b = 0; b < B_; ++b) red[g * 1024 + b * 64 + d] = s0[b];
    __syncthreads();
    if (t < 64) {
        #pragma unroll
        for (int b = 0; b < B_; ++b) {
            float s = red[b * 64 + t] + red[1024 + b * 64 + t]
                    + red[2048 + b * 64 + t] + red[3072 + b * 64 + t];
            part[(size_t)ib * BND + (size_t)(b * N_ + n) * D_ + t] = s;
        }
    }

    // Fire-and-forget xh stores at the very end.
    #pragma unroll
    for (int ii = 0; ii < 4; ++ii) {
        const int i = i0 + g * 4 + ii;
        #pragma unroll
        for (int j = 0; j < 8; ++j) {
            unsigned int v = pk[ii][j];
            unsigned short lo = (unsigned short)(v & 0xffffu);
            unsigned short hi = (unsigned short)(v >> 16);
            xh[((size_t)((2*j)   * N_ + n) * I_ + i) * D_ + d] = __builtin_bit_cast(__hip_bfloat16, lo);
            xh[((size_t)((2*j+1) * N_ + n) * I_ + i) * D_ + d] = __builtin_bit_cast(__hip_bfloat16, hi);
        }
    }
}

// K2: coef = squash(mean over i of x_hat) — iteration 0 (softmax of zeros is uniform)
__global__ __launch_bounds__(256) void k_out0(const float* __restrict__ part,
                                              float* __restrict__ coef) {
    const int t = blockIdx.x * 256 + threadIdx.x;   // 0..BND-1
    float s = 0.0f;
    for (int j = 0; j < IB; ++j) s += part[(size_t)j * BND + t];
    s *= (1.0f / (float)I_);
    coef[t] = squash1(s);
}

// K3/K4: one routing iteration over bf16 x_hat. logits l_i = x*coef.
// Online softmax over i (exp2 domain), s = sum c*x.
// final=0: coef += squash(s). final=1: out = squash(s).
// grid = B_*N_ blocks, 512 threads (8 i-stripes of 144, lane = d).
__global__ __launch_bounds__(512) void k_route(const __hip_bfloat16* __restrict__ xh,
                                               const float* __restrict__ coef_in,
                                               float* __restrict__ outp,
                                               int final_) {
    const int bx = blockIdx.x;             // b*N_ + n
    const int t  = threadIdx.x;
    const int d  = t & 63;
    const int g  = t >> 6;
    const __hip_bfloat16* base = xh + (size_t)bx * (I_ * D_);
    const float c  = coef_in[bx * D_ + d];
    const float c2 = c * LOG2E;

    float m = -INFINITY, Z = 0.0f, A = 0.0f;
    const int i0 = g * (I_ / 8);           // 144 per stripe
    #pragma unroll 4
    for (int j = 0; j < I_ / 8; ++j) {
        float x  = __bfloat162float(base[(size_t)(i0 + j) * D_ + d]);
        float l  = x * c2;
        float nm = fmaxf(m, l);
        float e1 = EXP2(m - nm);
        float e2 = EXP2(l - nm);
        Z = Z * e1 + e2;
        A = A * e1 + e2 * x;
        m = nm;
    }

    __shared__ float ms[512], zs[512], as_[512];
    ms[t] = m; zs[t] = Z; as_[t] = A;
    __syncthreads();
    if (t < 64) {
        float M = -INFINITY;
        #pragma unroll
        for (int gg = 0; gg < 8; ++gg) M = fmaxf(M, ms[gg * 64 + t]);
        float Zt = 0.0f, At = 0.0f;
        #pragma unroll
        for (int gg = 0; gg < 8; ++gg) {
            float e = EXP2(ms[gg * 64 + t] - M);
            Zt += zs[gg * 64 + t] * e;
            At += as_[gg * 64 + t] * e;
        }
        float s = At / Zt;
        float o = squash1(s);
        if (final_) outp[bx * D_ + t] = o;
        else        outp[bx * D_ + t] = c + o;
    }
}

extern "C" void kernel_launch(void* const* d_in, const int* in_sizes, int n_in,
                              void* d_out, int out_size, void* d_ws, size_t ws_size,
                              hipStream_t stream) {
    const float* inp = (const float*)d_in[0];
    const float* W   = (const float*)d_in[1];
    float* out  = (float*)d_out;

    __hip_bfloat16* xh = (__hip_bfloat16*)d_ws;               // 37,748,736 bf16 (75.5 MB)
    float* part = (float*)((char*)d_ws + (size_t)B_ * N_ * I_ * D_ * 2);  // 72*32768 floats
    float* coef = part + (size_t)IB * BND;                    // 32768 floats

    k_xhat <<<dim3(N_ * IB), dim3(256), 0, stream>>>(inp, W, xh, part);
    k_out0 <<<dim3(BND / 256), dim3(256), 0, stream>>>(part, coef);
    k_route<<<dim3(B_ * N_), dim3(512), 0, stream>>>(xh, coef, coef, 0);
    k_route<<<dim3(B_ * N_), dim3(512), 0, stream>>>(xh, coef, out, 1);
}